// Round 6
// baseline (9244.347 us; speedup 1.0000x reference)
//
#include <hip/hip_runtime.h>

typedef unsigned char u8;
typedef unsigned short u16;
typedef unsigned int u32;
typedef unsigned long long u64;
typedef __attribute__((ext_vector_type(8))) short short8;   // 8 x bf16
typedef __attribute__((ext_vector_type(4))) float f32x4;
typedef __attribute__((ext_vector_type(4))) int i32x4;

#define SEQ 512

// ---- ws layout (bytes); total 42,487,808 (< 46.4MB proven available) ----
#define OFF_XB   0ull          // 32 MB : xbF [c 128][g 8][mt 2][ks 16][lane 64][8] bf16
#define OFF_WXP  33554432ull   //  4 MB : Wxp [slot 32][w 2][q 4][ks 16][lane 64][8] bf16
#define OFF_WHQ  37748736ull   //  4 MB : Whq [slot 32][w 2][q 4][ks 16][lane 64][16] i8
                               //         (per-(slot,g) 16KB reused as private gates_x ring)
#define OFF_SCL  41943040ull   // 16 KB : scale[4096] f32 (= max|col|/127)
#define OFF_HIMG 41959424ull   // 512 KB: himg [g 8][par 2][hl 2][ks 16][lane 64][16] i8
#define OFF_TAG  42483712ull   //  2 KB : tags [g 8][64] u32
#define OFF_CTL  42485760ull   //  2 KB : xcnt[8]@x*64 ; fill[32]@512+s*4

// ---------- helpers ----------
__device__ inline u16 f2bf(float f) {
  u32 u = __float_as_uint(f);
  return (u16)((u + 0x7fffu + ((u >> 16) & 1u)) >> 16);   // RNE
}
__device__ inline float bf2f(u16 u) { return __uint_as_float(((u32)u) << 16); }
__device__ inline float sigm(float x) { return 1.f / (1.f + __expf(-x)); }
__device__ inline float tanh_(float x) { return 1.f - 2.f / (1.f + __expf(2.f * x)); }

#define SLD(p) __hip_atomic_load((p), __ATOMIC_RELAXED, __HIP_MEMORY_SCOPE_SYSTEM)
#define ALD(p) __hip_atomic_load((p), __ATOMIC_RELAXED, __HIP_MEMORY_SCOPE_AGENT)

#define MFMA_BF16(a, b, c_) __builtin_amdgcn_mfma_f32_16x16x32_bf16(a, b, c_, 0, 0, 0)
#define MFMA_I8(a, b, c_)   __builtin_amdgcn_mfma_i32_16x16x64_i8(a, b, c_, 0, 0, 0)

// ---------- prep: x [B][S][I] f32 -> chunked A-fragment image bf16 ----------
// (tau,brow,k): c=tau>>2, tc=tau&3, g=brow>>3, rb=brow&7; mrow=tc*8+rb;
// mt=mrow>>4; lane=((k>>3)&3)*16+(mrow&15); ks=k>>5; j=k&7
__global__ void pack_x(const float* __restrict__ x, u16* __restrict__ xb) {
  const int id = blockIdx.x * 256 + threadIdx.x;   // 2,097,152
  const int k8 = id & 63;
  const int brow = (id >> 6) & 63;
  const int tau = id >> 12;
  const float* src = x + ((size_t)(brow * SEQ + tau) << 9) + k8 * 8;
  float4 a = *(const float4*)src;
  float4 b = *(const float4*)(src + 4);
  uint4 v;
  v.x = (u32)f2bf(a.x) | ((u32)f2bf(a.y) << 16);
  v.y = (u32)f2bf(a.z) | ((u32)f2bf(a.w) << 16);
  v.z = (u32)f2bf(b.x) | ((u32)f2bf(b.y) << 16);
  v.w = (u32)f2bf(b.z) | ((u32)f2bf(b.w) << 16);
  const int c = tau >> 2, tc = tau & 3, g = brow >> 3, rb = brow & 7;
  const int mrow = tc * 8 + rb;
  const int mt = mrow >> 4;
  const int lane = (k8 & 3) * 16 + (mrow & 15);
  const int ks = k8 >> 2;
  *(uint4*)(xb + ((size_t)(((c * 8 + g) * 2 + mt) * 16 + ks) * 64 + lane) * 8) = v;
}

// ---------- prep: per-gate-column scales of W_h ----------
__global__ void calc_scales(const float* __restrict__ W0, const float* __restrict__ W1,
                            const float* __restrict__ W2, const float* __restrict__ W3,
                            float* __restrict__ scl) {
  const int n = blockIdx.x * 256 + threadIdx.x;     // 4096
  const int q = n >> 10, cc = n & 1023;
  const float* Wg = q == 0 ? W0 : q == 1 ? W1 : q == 2 ? W2 : W3;
  float mx = 1e-8f;
  for (int k = 0; k < 1024; ++k) mx = fmaxf(mx, fabsf(Wg[(size_t)(512 + k) * 1024 + cc]));
  scl[n] = mx / 127.f;
}

// ---------- prep: W_h -> i8 B-fragment image ----------
// unit id -> [slot][w][q][ks][lane][16]: col=q*1024+slot*32+w*16+(lane&15);
// k = ks*64 + (lane>>4)*16 + j
__global__ void pack_whq(const float* __restrict__ W0, const float* __restrict__ W1,
                         const float* __restrict__ W2, const float* __restrict__ W3,
                         const float* __restrict__ scl, u8* __restrict__ whq) {
  const int id = blockIdx.x * 256 + threadIdx.x;    // 262,144 units
  const int lane = id & 63;
  const int ks = (id >> 6) & 15;
  const int q = (id >> 10) & 3;
  const int w = (id >> 12) & 1;
  const int slot = id >> 13;
  const int col = q * 1024 + slot * 32 + w * 16 + (lane & 15);
  const int cc = col & 1023;
  const float* Wg = q == 0 ? W0 : q == 1 ? W1 : q == 2 ? W2 : W3;
  const int k0 = ks * 64 + (lane >> 4) * 16;
  const float inv_s = 1.f / scl[col];
  u8 tmp[16];
#pragma unroll
  for (int j = 0; j < 16; ++j) {
    float v = Wg[(size_t)(512 + k0 + j) * 1024 + cc] * inv_s;
    int iv = (int)rintf(fminf(fmaxf(v, -127.f), 127.f));
    tmp[j] = (u8)(signed char)iv;
  }
  *(uint4*)(whq + (size_t)id * 16) = *(uint4*)tmp;
}

// ---------- prep: W_x -> bf16 B-fragment image ----------
__global__ void pack_wxp(const float* __restrict__ W0, const float* __restrict__ W1,
                         const float* __restrict__ W2, const float* __restrict__ W3,
                         u16* __restrict__ wxp) {
  const int id = blockIdx.x * 256 + threadIdx.x;    // 262,144 units
  const int lane = id & 63;
  const int ks = (id >> 6) & 15;
  const int q = (id >> 10) & 3;
  const int w = (id >> 12) & 1;
  const int slot = id >> 13;
  const int col = q * 1024 + slot * 32 + w * 16 + (lane & 15);
  const int cc = col & 1023;
  const float* Wg = q == 0 ? W0 : q == 1 ? W1 : q == 2 ? W2 : W3;
  const int k0 = ks * 32 + (lane >> 4) * 8;
  u16 tmp[8];
#pragma unroll
  for (int j = 0; j < 8; ++j) tmp[j] = f2bf(Wg[(size_t)(k0 + j) * 1024 + cc]);
  *(uint4*)(wxp + (size_t)id * 8) = *(uint4*)tmp;
}

// ---------- main persistent kernel ----------
// 256 blocks x 128 thr (2 waves). group g = XCD id; slot via per-XCD L2 atomic.
// Block: batch rows [8g,8g+8), h-cols [32*slot, +32); wave w = 16-col half.
// W_h i8 in LDS; h published as i8 hi/lo A-fragments in group-private L2 image;
// per-wave tags, release/acquire at agent scope. gates_x self-produced ring.
__global__ void __launch_bounds__(128) lstm_main(
    char* __restrict__ ws,
    const float* __restrict__ b_i, const float* __restrict__ b_f,
    const float* __restrict__ b_c, const float* __restrict__ b_o,
    const float* __restrict__ fcw, const float* __restrict__ fcb,
    float* __restrict__ out) {
  __shared__ struct { u8 wh[131072]; u8 al[32768]; } sh;   // 163,840 B

  const int tid = threadIdx.x;
  const int w = tid >> 6;
  const int lane = tid & 63;
  const int kgrp = lane >> 4;
  const int l15 = lane & 15;

  u32 xcd;
  asm volatile("s_getreg_b32 %0, hwreg(HW_REG_XCC_ID, 0, 8)" : "=s"(xcd));
  const int g = (int)(xcd & 7);

  u32* ctl = (u32*)(ws + OFF_CTL);
  u32* tags = (u32*)(ws + OFF_TAG) + g * 64;
  u8* himg = (u8*)(ws + OFF_HIMG) + (size_t)g * 65536;

  // ---- slot election (L2-local) ----
  if (tid == 0) {
    u32 s = __hip_atomic_fetch_add(ctl + (xcd & 7) * 16, 1u, __ATOMIC_RELAXED,
                                   __HIP_MEMORY_SCOPE_AGENT);
    *(volatile u32*)&sh.al[0] = s;
  }
  __syncthreads();
  const int slot = (int)*(volatile u32*)&sh.al[0];
  __syncthreads();
  if (slot >= 32) return;   // cannot happen (1 block/CU pigeonhole)

  const u8* whq = (const u8*)(ws + OFF_WHQ) + (size_t)slot * 131072;
  const u16* wxp = (const u16*)(ws + OFF_WXP) + ((size_t)(slot * 2 + w) * 4) * 16 * 64 * 8;
  const u16* xbE = (const u16*)(ws + OFF_XB);
  u16* ringE = (u16*)(ws + OFF_WHQ) + ((size_t)slot * 131072 + (size_t)g * 16384) / 2;

  // ---- fill W_h LDS (128 KB) ----
#pragma unroll 4
  for (int i = 0; i < 64; ++i) {
    int off = (i * 128 + tid) * 16;
    *(uint4*)&sh.wh[off] = *(const uint4*)(whq + off);
  }
  // ---- zero A-LDS (rows 8..15 stay zero forever) ----
#pragma unroll 4
  for (int i = 0; i < 16; ++i) {
    uint4 z = {0, 0, 0, 0};
    *(uint4*)&sh.al[(i * 128 + tid) * 16] = z;
  }
  __syncthreads();
  // ---- cross-XCD fill barrier for this slot's Whq slice (one-time) ----
  if (tid == 0) {
    __hip_atomic_fetch_add(ctl + 128 + slot, 1u, __ATOMIC_RELEASE, __HIP_MEMORY_SCOPE_SYSTEM);
    while (SLD(ctl + 128 + slot) < 8u) __builtin_amdgcn_s_sleep(1);
  }
  __syncthreads();

  // ---- per-thread constants ----
  const int hcol = slot * 32 + w * 16 + l15;
  float sA[4], sB[4], bq[4];
  {
    const float* scl = (const float*)(ws + OFF_SCL);
#pragma unroll
    for (int q = 0; q < 4; ++q) {
      float s = scl[q * 1024 + hcol];
      sA[q] = s / 127.f;
      sB[q] = s / 32258.f;
    }
    bq[0] = b_i[hcol]; bq[1] = b_f[hcol]; bq[2] = b_c[hcol]; bq[3] = b_o[hcol];
  }

  // ---- x-chunk GEMM: gates_x for 4 steps -> private ring (bf16) ----
#define XCHUNK(c)                                                              \
  {                                                                            \
    f32x4 ax[2][4];                                                            \
    _Pragma("unroll") for (int m = 0; m < 2; ++m)                              \
      _Pragma("unroll") for (int q = 0; q < 4; ++q)                            \
        ax[m][q] = (f32x4){0.f, 0.f, 0.f, 0.f};                                \
    _Pragma("unroll 4") for (int ks = 0; ks < 16; ++ks) {                      \
      short8 a0 = *(const short8*)(xbE + ((size_t)(((c) * 8 + g) * 2 + 0) * 16 + ks) * 512 + lane * 8); \
      short8 a1 = *(const short8*)(xbE + ((size_t)(((c) * 8 + g) * 2 + 1) * 16 + ks) * 512 + lane * 8); \
      _Pragma("unroll") for (int q = 0; q < 4; ++q) {                          \
        short8 b = *(const short8*)(wxp + ((size_t)(q * 16 + ks) * 64 + lane) * 8); \
        ax[0][q] = MFMA_BF16(a0, b, ax[0][q]);                                 \
        ax[1][q] = MFMA_BF16(a1, b, ax[1][q]);                                 \
      }                                                                        \
    }                                                                          \
    u16* rb = ringE + ((c) & 1) * 4096;                                        \
    const int tc2 = (kgrp >> 1), lc = (kgrp & 1) * 16 + l15;                   \
    _Pragma("unroll") for (int m = 0; m < 2; ++m)                              \
      _Pragma("unroll") for (int q = 0; q < 4; ++q) {                          \
        u64 pk = 0;                                                            \
        _Pragma("unroll") for (int r = 0; r < 4; ++r)                          \
          pk |= (u64)f2bf(ax[m][q][r] + bq[q]) << (16 * r);                    \
        *(u64*)(rb + ((((m * 2 + tc2) * 2 + w) * 4 + q) * 32 + lc) * 4) = pk;  \
      }                                                                        \
  }

  XCHUNK(0);
  XCHUNK(1);

  float cs[4] = {0.f, 0.f, 0.f, 0.f};   // cell state rows kgrp*4+r (kgrp<2 real)
  const int kgc = kgrp & 1;             // clamped for safe ring addressing

  for (int t = 1; t <= SEQ; ++t) {
    const int tau = t - 1;
    const int par_r = tau & 1, par_w = t & 1;

    // ---- private gates_x load (prefetch; hidden under poll) ----
    f32x4 gx[4];
    {
      const u16* rb = ringE + ((tau >> 2) & 1) * 4096;
      const int tc = tau & 3;
#pragma unroll
      for (int q = 0; q < 4; ++q) {
        u64 pk = *(const u64*)(rb + (((tc * 2 + w) * 4 + q) * 32 + kgc * 16 + l15) * 4);
        gx[q][0] = bf2f((u16)pk);        gx[q][1] = bf2f((u16)(pk >> 16));
        gx[q][2] = bf2f((u16)(pk >> 32)); gx[q][3] = bf2f((u16)(pk >> 48));
      }
    }
    // ---- poll own group's 64 per-wave tags (L2-local) ----
    {
      const u32 tgt = (u32)tau;
      u32 v;
      do { v = ALD(tags + lane); } while (!__all(v >= tgt));
      __builtin_amdgcn_fence(__ATOMIC_ACQUIRE, "agent");
    }
    // ---- stage A (hi/lo i8 fragments) into LDS; wave w handles hl=w ----
    {
      const u8* src = himg + (size_t)((par_r * 2 + w) * 16) * 1024 + lane * 16;
      if (l15 < 8) {
#pragma unroll 4
        for (int ks = 0; ks < 16; ++ks) {
          uint4 v = *(const uint4*)(src + ks * 1024);
          *(uint4*)&sh.al[((w * 16 + ks) * 64 + lane) * 16] = v;
        }
      }
    }
    __syncthreads();
    // ---- h-part MFMA: 4 gates x 16 ks x {hi,lo} ----
    i32x4 acch[4], accl[4];
#pragma unroll
    for (int q = 0; q < 4; ++q) { acch[q] = (i32x4){0,0,0,0}; accl[q] = (i32x4){0,0,0,0}; }
#pragma unroll 4
    for (int ks = 0; ks < 16; ++ks) {
      i32x4 ah = *(const i32x4*)&sh.al[((0 * 16 + ks) * 64 + lane) * 16];
      i32x4 alo = *(const i32x4*)&sh.al[((1 * 16 + ks) * 64 + lane) * 16];
#pragma unroll
      for (int q = 0; q < 4; ++q) {
        i32x4 b = *(const i32x4*)&sh.wh[(((w * 4 + q) * 16 + ks) * 64 + lane) * 16];
        acch[q] = MFMA_I8(ah, b, acch[q]);
        accl[q] = MFMA_I8(alo, b, accl[q]);
      }
    }
    __syncthreads();   // A-LDS reads done before stg alias writes
    // ---- gates, cell state, quantize, stage to LDS ----
    {
#pragma unroll
      for (int r = 0; r < 4; ++r) {
        float gq[4];
#pragma unroll
        for (int q = 0; q < 4; ++q)
          gq[q] = sA[q] * (float)acch[q][r] + sB[q] * (float)accl[q][r] + gx[q][r];
        float iv = sigm(gq[0]);
        float fv = sigm(gq[1]);
        float gv = tanh_(gq[2]);
        float ov = sigm(gq[3]);
        float cn = fv * cs[r] + iv * gv;
        cs[r] = cn;
        float h = ov * tanh_(cn);
        float hs = h * 127.f;
        float hi = rintf(hs);
        float lo = rintf((hs - hi) * 254.f);
        if (kgrp < 2) {
          int row = kgrp * 4 + r;
          sh.al[w * 256 + row * 16 + l15] = (u8)(signed char)(int)hi;
          sh.al[w * 256 + 128 + row * 16 + l15] = (u8)(signed char)(int)lo;
        }
      }
    }
    __syncthreads();
    // ---- publish 16 units (8 hi + 8 lo) + release tag ----
    if (lane < 16) {
      const int hl = lane >> 3, row = lane & 7;
      uint4 v = *(const uint4*)&sh.al[w * 256 + hl * 128 + row * 16];
      u8* dst = himg + (size_t)(((par_w * 2 + hl) * 16 + (slot >> 1)) * 64 +
                                ((slot & 1) * 2 + w) * 16 + row) * 16;
      *(uint4*)dst = v;
    }
    if (lane == 0)
      __hip_atomic_store(tags + slot * 2 + w, (u32)t, __ATOMIC_RELEASE,
                         __HIP_MEMORY_SCOPE_AGENT);
    // ---- produce next ring chunk (self-paced, off critical path) ----
    if ((t & 3) == 1 && t > 4) {
      int cn = (tau >> 2) + 1;
      if (cn < 128) XCHUNK(cn);
    }
  }

  // ---- FC epilogue: out[rows 8g..][cols slot*16..] from h_512 (parity 0) ----
  {
    u32 v;
    do { v = ALD(tags + lane); } while (!__all(v >= (u32)SEQ));
    __builtin_amdgcn_fence(__ATOMIC_ACQUIRE, "agent");
  }
  {
    const int row = tid >> 4;          // 0..7
    const int c16 = tid & 15;
    const int col = slot * 16 + c16;
    const float* wr = fcw + (size_t)col * 1024;
    float acc = fcb[col];
    const float C1 = 1.f / 127.f, C2 = 1.f / 32258.f;
    for (int ks = 0; ks < 16; ++ks) {
#pragma unroll
      for (int kg = 0; kg < 4; ++kg) {
        union { uint4 v; signed char b[16]; } hi, lo;
        hi.v = *(const uint4*)(himg + (size_t)((0 * 16 + ks) * 64 + kg * 16 + row) * 16);
        lo.v = *(const uint4*)(himg + (size_t)((1 * 16 + ks) * 64 + kg * 16 + row) * 16);
        const float* wp = wr + ks * 64 + kg * 16;
#pragma unroll
        for (int j = 0; j < 16; ++j) {
          float h = (float)hi.b[j] * C1 + (float)lo.b[j] * C2;
          acc += h * wp[j];
        }
      }
    }
    out[(size_t)(g * 8 + row) * 512 + col] = acc;
  }
}

// ---------- launch ----------
extern "C" void kernel_launch(void* const* d_in, const int* in_sizes, int n_in,
                              void* d_out, int out_size, void* d_ws, size_t ws_size,
                              hipStream_t stream) {
  const float* x  = (const float*)d_in[0];
  const float* W0 = (const float*)d_in[1];
  const float* W1 = (const float*)d_in[2];
  const float* W2 = (const float*)d_in[3];
  const float* W3 = (const float*)d_in[4];
  const float* bi = (const float*)d_in[5];
  const float* bf = (const float*)d_in[6];
  const float* bc = (const float*)d_in[7];
  const float* bo = (const float*)d_in[8];
  const float* fcw = (const float*)d_in[9];
  const float* fcb = (const float*)d_in[10];
  float* out = (float*)d_out;

  char* ws = (char*)d_ws;
  u16* xbp = (u16*)(ws + OFF_XB);
  u16* wxp = (u16*)(ws + OFF_WXP);
  u8* whq  = (u8*)(ws + OFF_WHQ);
  float* scl = (float*)(ws + OFF_SCL);

  pack_x<<<dim3(8192), dim3(256), 0, stream>>>(x, xbp);
  calc_scales<<<dim3(16), dim3(256), 0, stream>>>(W0, W1, W2, W3, scl);
  pack_whq<<<dim3(1024), dim3(256), 0, stream>>>(W0, W1, W2, W3, scl, whq);
  pack_wxp<<<dim3(1024), dim3(256), 0, stream>>>(W0, W1, W2, W3, wxp);
  // zero himg + tags + ctl (528,384 B contiguous)
  hipMemsetAsync(ws + OFF_HIMG, 0, 524288 + 2048 + 2048, stream);
  lstm_main<<<dim3(256), dim3(128), 0, stream>>>(ws, bi, bf, bc, bo, fcw, fcb, out);
}

// Round 8
// 2255.119 us; speedup vs baseline: 4.0993x; 4.0993x over previous
//
#include <hip/hip_runtime.h>

typedef unsigned char u8;
typedef unsigned short u16;
typedef unsigned int u32;
typedef unsigned long long u64;
typedef __attribute__((ext_vector_type(4))) int i32x4;
typedef __attribute__((ext_vector_type(4))) float f32x4;

#define SEQ 512

// ---- ws layout (bytes); total 40,567,296 ----
#define OFF_XBQ  0ull          // 32 MB : xbq [c 128][g 8][hl 2][mt 2][ks 8][lane 64][16] i8
#define OFF_WXQ  33554432ull   //  2 MB : wxq [slot 32][w 2][q 4][ks 8][lane 64][16] i8
#define OFF_WHQ  35651584ull   //  4 MB : whq [slot 32][w 2][q 4][ks 16][lane 64][16] i8
#define OFF_SCL  39845888ull   // 32 KB : scl [part 2][q 4][1024] f32 (0:x, 1:h; = max|col|/127)
#define OFF_SXG  39878656ull   // 128 KB: sxg [tau 512][brow 64] f32 per-token x scale
#define OFF_HIMG 40009728ull   // 512 KB: himg [g 8][par 2][hl 2][ks 16][lane 64][16] i8
#define OFF_TAG  40534016ull   // 32 KB : tags [g 8][64] u32, 64B stride
#define OFF_CTL  40566784ull   // 512 B : xcnt[8] @ g*64

// ---------- helpers ----------
__device__ inline u16 f2bf(float f) {
  u32 u = __float_as_uint(f);
  return (u16)((u + 0x7fffu + ((u >> 16) & 1u)) >> 16);   // RNE
}
__device__ inline float bf2f(u16 u) { return __uint_as_float(((u32)u) << 16); }
__device__ inline float sigm(float x) { return 1.f / (1.f + __expf(-x)); }
__device__ inline float tanh_(float x) { return 1.f - 2.f / (1.f + __expf(2.f * x)); }

#define MFMA_I8(a, b, c_) __builtin_amdgcn_mfma_i32_16x16x64_i8(a, b, c_, 0, 0, 0)

// device(agent)-scope relaxed atomics: bypass L1, serviced at own-XCD L2,
// NO cache-maintenance (relaxed). Proven polling/data path from rounds 5/6.
__device__ inline u32 ald32(const u32* p) {
  return __hip_atomic_load(p, __ATOMIC_RELAXED, __HIP_MEMORY_SCOPE_AGENT);
}
__device__ inline void ast32(u32* p, u32 v) {
  __hip_atomic_store(p, v, __ATOMIC_RELAXED, __HIP_MEMORY_SCOPE_AGENT);
}
__device__ inline i32x4 ald128(const void* p) {
  union { u64 q[2]; i32x4 v; } u;
  u.q[0] = __hip_atomic_load((const u64*)p, __ATOMIC_RELAXED, __HIP_MEMORY_SCOPE_AGENT);
  u.q[1] = __hip_atomic_load((const u64*)p + 1, __ATOMIC_RELAXED, __HIP_MEMORY_SCOPE_AGENT);
  return u.v;
}
#define VMWAIT0() asm volatile("s_waitcnt vmcnt(0)" ::: "memory")
#define CBAR()    asm volatile("" ::: "memory")

// ---------- prep: x -> per-token-scaled i8 hi/lo A-fragment image ----------
__global__ void pack_xq(const float* __restrict__ x, u8* __restrict__ xbq,
                        float* __restrict__ sxg) {
  __shared__ u8 st[1024];
  const int bid = blockIdx.x;           // brow*512 + tau (32768 blocks, 64 thr)
  const int brow = bid >> 9, tau = bid & 511;
  const int lane = threadIdx.x;
  const float* src = x + ((size_t)bid << 9) + lane * 8;
  float4 a = *(const float4*)src;
  float4 b = *(const float4*)(src + 4);
  float v[8] = {a.x, a.y, a.z, a.w, b.x, b.y, b.z, b.w};
  float m = 0.f;
#pragma unroll
  for (int j = 0; j < 8; ++j) m = fmaxf(m, fabsf(v[j]));
#pragma unroll
  for (int i = 1; i < 64; i <<= 1) m = fmaxf(m, __shfl_xor(m, i));
  m = fmaxf(m, 1e-20f);
  const float s = m * (1.f / 127.f), inv = 127.f / m;
#pragma unroll
  for (int j = 0; j < 8; ++j) {
    float t = v[j] * inv;                 // |t| <= 127
    float hi = rintf(t);
    float lo = rintf((t - hi) * 254.f);
    st[lane * 8 + j] = (u8)(signed char)(int)hi;
    st[512 + lane * 8 + j] = (u8)(signed char)(int)lo;
  }
  __syncthreads();
  const int hl = lane >> 5, ks = (lane >> 2) & 7, kg = lane & 3;
  uint4 u = *(const uint4*)&st[hl * 512 + ks * 64 + kg * 16];
  const int c = tau >> 2, tc = tau & 3, g = brow >> 3, rb = brow & 7;
  const int mrow = tc * 8 + rb, mt = mrow >> 4, m15 = mrow & 15;
  *(uint4*)(xbq + (size_t)(((((c * 8 + g) * 2 + hl) * 2 + mt) * 8 + ks) * 64 +
                           kg * 16 + m15) * 16) = u;
  if (lane == 0) sxg[tau * 64 + brow] = s;
}

// ---------- prep: per-gate-column scales ----------
__global__ void calc_scales(const float* __restrict__ W0, const float* __restrict__ W1,
                            const float* __restrict__ W2, const float* __restrict__ W3,
                            float* __restrict__ scl) {
  const int id = blockIdx.x * 256 + threadIdx.x;   // 8192
  const int part = id >> 12, q = (id >> 10) & 3, cc = id & 1023;
  const float* Wg = q == 0 ? W0 : q == 1 ? W1 : q == 2 ? W2 : W3;
  const int r0 = part ? 512 : 0, n = part ? 1024 : 512;
  float mx = 1e-8f;
  for (int k = 0; k < n; ++k) mx = fmaxf(mx, fabsf(Wg[(size_t)(r0 + k) * 1024 + cc]));
  scl[id] = mx * (1.f / 127.f);
}

// ---------- prep: W_h -> i8 B-fragment image (K=1024) ----------
__global__ void pack_whq(const float* __restrict__ W0, const float* __restrict__ W1,
                         const float* __restrict__ W2, const float* __restrict__ W3,
                         const float* __restrict__ scl, u8* __restrict__ whq) {
  const int id = blockIdx.x * 256 + threadIdx.x;    // 262,144 units
  const int lane = id & 63, ks = (id >> 6) & 15, q = (id >> 10) & 3;
  const int w = (id >> 12) & 1, slot = id >> 13;
  const int hcol = slot * 32 + w * 16 + (lane & 15);
  const float* Wg = q == 0 ? W0 : q == 1 ? W1 : q == 2 ? W2 : W3;
  const int k0 = ks * 64 + (lane >> 4) * 16;
  const float inv_s = 1.f / scl[4096 + q * 1024 + hcol];
  u8 tmp[16];
#pragma unroll
  for (int j = 0; j < 16; ++j) {
    float v = Wg[(size_t)(512 + k0 + j) * 1024 + hcol] * inv_s;
    tmp[j] = (u8)(signed char)(int)rintf(fminf(fmaxf(v, -127.f), 127.f));
  }
  *(uint4*)(whq + (size_t)id * 16) = *(uint4*)tmp;
}

// ---------- prep: W_x -> i8 B-fragment image (K=512) ----------
__global__ void pack_wxq(const float* __restrict__ W0, const float* __restrict__ W1,
                         const float* __restrict__ W2, const float* __restrict__ W3,
                         const float* __restrict__ scl, u8* __restrict__ wxq) {
  const int id = blockIdx.x * 256 + threadIdx.x;    // 131,072 units
  const int lane = id & 63, ks = (id >> 6) & 7, q = (id >> 9) & 3;
  const int w = (id >> 11) & 1, slot = id >> 12;
  const int hcol = slot * 32 + w * 16 + (lane & 15);
  const float* Wg = q == 0 ? W0 : q == 1 ? W1 : q == 2 ? W2 : W3;
  const int k0 = ks * 64 + (lane >> 4) * 16;
  const float inv_s = 1.f / scl[q * 1024 + hcol];
  u8 tmp[16];
#pragma unroll
  for (int j = 0; j < 16; ++j) {
    float v = Wg[(size_t)(k0 + j) * 1024 + hcol] * inv_s;
    tmp[j] = (u8)(signed char)(int)rintf(fminf(fmaxf(v, -127.f), 127.f));
  }
  *(uint4*)(wxq + (size_t)id * 16) = *(uint4*)tmp;
}

// ---------- main persistent kernel ----------
// 256 blocks x 192 thr (3 waves). group g = XCD id (all sync/data intra-XCD L2).
// waves 0,1: consumers: h-part i8 MFMA + gates + publish. wave 2: gates_x
// producer -> 2-chunk LDS ring. No fences, no in-loop barriers.
__global__ void __launch_bounds__(192, 1) lstm_main(
    char* __restrict__ ws,
    const float* __restrict__ b_i, const float* __restrict__ b_f,
    const float* __restrict__ b_c, const float* __restrict__ b_o,
    const float* __restrict__ fcw, const float* __restrict__ fcb,
    float* __restrict__ out) {
  __shared__ __align__(16) u8 wh[131072];      // [w 2][q 4][ks 16][lane 64][16]
  __shared__ __align__(16) u16 ring_[8192];    // [par 2][tc 4][cc 128][rb 8] bf16
  __shared__ __align__(16) u8 pub_[1024];      // per-wave 512B publish staging
  __shared__ u32 flg[16];                      // 0:slot 1:pc 2,3:ct[w]

  const int tid = threadIdx.x;
  const int wid = tid >> 6;
  const int lane = tid & 63;
  const int kgrp = lane >> 4;
  const int l15 = lane & 15;

  u32 xcd;
  asm volatile("s_getreg_b32 %0, hwreg(HW_REG_XCC_ID, 0, 8)" : "=s"(xcd));
  const int g = (int)(xcd & 7);

  if (tid == 0) {
    u32 s = __hip_atomic_fetch_add((u32*)(ws + OFF_CTL) + g * 16, 1u,
                                   __ATOMIC_RELAXED, __HIP_MEMORY_SCOPE_SYSTEM);
    flg[0] = s; flg[1] = 0; flg[2] = 0; flg[3] = 0;
  }
  __syncthreads();
  const int slot = (int)flg[0];
  if (slot >= 32) return;   // cannot happen (1 block/CU pigeonhole)

  // one-time W_h LDS fill (8192 x 16B units, 192 threads)
  {
    const u8* src = (const u8*)(ws + OFF_WHQ) + (size_t)slot * 131072;
    for (int i = 0; i < 43; ++i) {
      int u = i * 192 + tid;
      if (u < 8192) *(uint4*)&wh[u * 16] = *(const uint4*)(src + u * 16);
    }
  }
  __syncthreads();

  u8* himg = (u8*)(ws + OFF_HIMG) + (size_t)g * 65536;
  u32* tags = (u32*)(ws + OFF_TAG) + g * 1024;
  const float* scl = (const float*)(ws + OFF_SCL);

  if (wid == 2) {
    // ================= producer wave: gates_x -> LDS ring =================
    const u8* xq = (const u8*)(ws + OFF_XBQ);
    const u8* wxs = (const u8*)(ws + OFF_WXQ) + (size_t)slot * 65536;
    const float* sxg = (const float*)(ws + OFF_SXG);
    float swx[2][4], bs[2][4];
#pragma unroll
    for (int w2 = 0; w2 < 2; ++w2) {
      const int cwq = slot * 32 + w2 * 16 + l15;
#pragma unroll
      for (int q = 0; q < 4; ++q) swx[w2][q] = scl[q * 1024 + cwq];
      bs[w2][0] = b_i[cwq]; bs[w2][1] = b_f[cwq];
      bs[w2][2] = b_c[cwq]; bs[w2][3] = b_o[cwq];
    }
    for (int c = 0; c < 128; ++c) {
      if (c >= 2) {
        const u32 need = (u32)(4 * c - 4);
        while (((volatile u32*)flg)[2] < need || ((volatile u32*)flg)[3] < need) {}
        CBAR();
      }
      float sxv[2][4];
#pragma unroll
      for (int mt = 0; mt < 2; ++mt)
#pragma unroll
        for (int r = 0; r < 4; ++r)
          sxv[mt][r] = sxg[(c * 4 + mt * 2 + (kgrp >> 1)) * 64 + g * 8 + (kgrp & 1) * 4 + r];
      i32x4 accH[2][2][4], accL[2][2][4];
#pragma unroll
      for (int mt = 0; mt < 2; ++mt)
#pragma unroll
        for (int w2 = 0; w2 < 2; ++w2)
#pragma unroll
          for (int q = 0; q < 4; ++q) {
            accH[mt][w2][q] = (i32x4){0, 0, 0, 0};
            accL[mt][w2][q] = (i32x4){0, 0, 0, 0};
          }
      const u8* xc = xq + (size_t)(c * 8 + g) * 32768;
#pragma unroll 2
      for (int ks = 0; ks < 8; ++ks) {
        i32x4 aH0 = *(const i32x4*)(xc + (size_t)((0 * 2 + 0) * 8 + ks) * 1024 + lane * 16);
        i32x4 aH1 = *(const i32x4*)(xc + (size_t)((0 * 2 + 1) * 8 + ks) * 1024 + lane * 16);
        i32x4 aL0 = *(const i32x4*)(xc + (size_t)((1 * 2 + 0) * 8 + ks) * 1024 + lane * 16);
        i32x4 aL1 = *(const i32x4*)(xc + (size_t)((1 * 2 + 1) * 8 + ks) * 1024 + lane * 16);
#pragma unroll
        for (int w2 = 0; w2 < 2; ++w2)
#pragma unroll
          for (int q = 0; q < 4; ++q) {
            i32x4 b = *(const i32x4*)(wxs + (size_t)(((w2 * 4 + q) * 8 + ks) * 64 + lane) * 16);
            accH[0][w2][q] = MFMA_I8(aH0, b, accH[0][w2][q]);
            accH[1][w2][q] = MFMA_I8(aH1, b, accH[1][w2][q]);
            accL[0][w2][q] = MFMA_I8(aL0, b, accL[0][w2][q]);
            accL[1][w2][q] = MFMA_I8(aL1, b, accL[1][w2][q]);
          }
      }
#pragma unroll
      for (int mt = 0; mt < 2; ++mt)
#pragma unroll
        for (int w2 = 0; w2 < 2; ++w2)
#pragma unroll
          for (int q = 0; q < 4; ++q) {
            u64 pk = 0;
#pragma unroll
            for (int r = 0; r < 4; ++r) {
              float val = sxv[mt][r] * swx[w2][q] *
                          ((float)accH[mt][w2][q][r] + (float)accL[mt][w2][q][r] * (1.f / 254.f)) +
                          bs[w2][q];
              pk |= (u64)f2bf(val) << (16 * r);
            }
            const int tc = mt * 2 + (kgrp >> 1);
            const int cc2 = (w2 * 4 + q) * 16 + l15;
            const int rb0 = (kgrp & 1) * 4;
            *(u64*)&ring_[(((c & 1) * 4 + tc) * 128 + cc2) * 8 + rb0] = pk;
          }
      asm volatile("s_waitcnt lgkmcnt(0)" ::: "memory");
      ((volatile u32*)flg)[1] = (u32)(c + 1);
    }
    return;
  }

  // ================= consumer waves (w = wid in {0,1}) =================
  const int w = wid;
  const int col = slot * 32 + w * 16 + l15;
  float sA[4], sB[4];
#pragma unroll
  for (int q = 0; q < 4; ++q) {
    float s = scl[4096 + q * 1024 + col];
    sA[q] = s * (1.f / 127.f);
    sB[q] = s * (1.f / 32258.f);
  }
  float cs[4] = {0.f, 0.f, 0.f, 0.f};
  u32* mytag = tags + (slot * 2 + w) * 16;
  const int rbb = (kgrp & 1) * 4;

  for (int t = 1; t <= SEQ; ++t) {
    const int tau = t - 1, ch = tau >> 2, tc = tau & 3, par = tau & 1;
    // gates_x from LDS ring
    while (((volatile u32*)flg)[1] <= (u32)ch) {}
    CBAR();
    f32x4 gx[4];
#pragma unroll
    for (int q = 0; q < 4; ++q) {
      u64 pk = *(const u64*)&ring_[(((ch & 1) * 4 + tc) * 128 + (w * 4 + q) * 16 + l15) * 8 + rbb];
      gx[q][0] = bf2f((u16)pk);         gx[q][1] = bf2f((u16)(pk >> 16));
      gx[q][2] = bf2f((u16)(pk >> 32)); gx[q][3] = bf2f((u16)(pk >> 48));
    }
    // wait until all 64 consumer-waves of this XCD published h_tau
    { u32 tv; do { tv = ald32(tags + lane * 16); } while (!__all(tv >= (u32)tau)); }
    CBAR();
    // h-part MFMA: two half-passes of {16 agent loads, 32 MFMA x2}
    const u8* hbp_ = himg + par * 32768 + lane * 16;
    i32x4 acH[4], acL[4];
#pragma unroll
    for (int q = 0; q < 4; ++q) { acH[q] = (i32x4){0,0,0,0}; acL[q] = (i32x4){0,0,0,0}; }
#pragma unroll
    for (int half = 0; half < 2; ++half) {
      i32x4 ah[8], al[8];
#pragma unroll
      for (int ks = 0; ks < 8; ++ks) {
        ah[ks] = ald128(hbp_ + (size_t)(half * 8 + ks) * 1024);
        al[ks] = ald128(hbp_ + (size_t)(16 + half * 8 + ks) * 1024);
      }
#pragma unroll
      for (int ks = 0; ks < 8; ++ks)
#pragma unroll
        for (int q = 0; q < 4; ++q) {
          i32x4 b = *(const i32x4*)&wh[(size_t)(((w * 4 + q) * 16 + half * 8 + ks) * 64 + lane) * 16];
          acH[q] = MFMA_I8(ah[ks], b, acH[q]);
          acL[q] = MFMA_I8(al[ks], b, acL[q]);
        }
    }
    // gates, cell state, quantize h (hi/lo i8), stage to LDS
#pragma unroll
    for (int r = 0; r < 4; ++r) {
      float p0 = sA[0] * (float)acH[0][r] + sB[0] * (float)acL[0][r] + gx[0][r];
      float p1 = sA[1] * (float)acH[1][r] + sB[1] * (float)acL[1][r] + gx[1][r];
      float p2 = sA[2] * (float)acH[2][r] + sB[2] * (float)acL[2][r] + gx[2][r];
      float p3 = sA[3] * (float)acH[3][r] + sB[3] * (float)acL[3][r] + gx[3][r];
      float iv = sigm(p0), fv = sigm(p1), gv = tanh_(p2), ov = sigm(p3);
      float cn = fv * cs[r] + iv * gv;
      cs[r] = cn;
      float h = ov * tanh_(cn);
      float hq = h * 127.f;
      float hi = rintf(hq);
      float lo = rintf((hq - hi) * 254.f);
      if (kgrp < 2) {
        pub_[w * 512 + (kgrp * 4 + r) * 16 + l15] = (u8)(signed char)(int)hi;
        pub_[w * 512 + 128 + (kgrp * 4 + r) * 16 + l15] = (u8)(signed char)(int)lo;
      }
    }
    asm volatile("s_waitcnt lgkmcnt(0)" ::: "memory");
    if (lane < 16) {
      const int hl = lane >> 3, row = lane & 7;
      uint4 v = *(const uint4*)&pub_[w * 512 + hl * 128 + row * 16];
      u8* dst = himg + (size_t)((((t & 1) * 2 + hl) * 16 + (slot >> 1)) * 64 +
                                ((slot & 1) * 2 + w) * 16 + row) * 16;
      *(uint4*)dst = v;   // plain store: write-through vL1 -> lands in own-XCD L2
    }
    VMWAIT0();            // h stores acked at L2 before tag release
    if (lane == 0) ast32(mytag, (u32)t);
    ((volatile u32*)flg)[2 + w] = (u32)t;
  }

  // ================= FC epilogue (h_512 = himg parity 0) =================
  { u32 tv; do { tv = ald32(tags + lane * 16); } while (!__all(tv >= (u32)SEQ)); }
  CBAR();
  {
    const int row = tid >> 4, c16 = tid & 15;
    const int ocol = slot * 16 + c16;
    const float* wr = fcw + (size_t)ocol * 1024;
    float acc = fcb[ocol];
    const float C1 = 1.f / 127.f, C2 = 1.f / 32258.f;
    for (int ks = 0; ks < 16; ++ks) {
#pragma unroll
      for (int kg = 0; kg < 4; ++kg) {
        union { i32x4 v; signed char b[16]; } H, L;
        H.v = ald128(himg + (size_t)(ks * 64 + kg * 16 + row) * 16);
        L.v = ald128(himg + (size_t)((16 + ks) * 64 + kg * 16 + row) * 16);
        const float* wp = wr + ks * 64 + kg * 16;
#pragma unroll
        for (int j = 0; j < 16; ++j)
          acc += ((float)H.b[j] * C1 + (float)L.b[j] * C2) * wp[j];
      }
    }
    out[(size_t)(g * 8 + row) * 512 + ocol] = acc;
  }
}

// ---------- launch ----------
extern "C" void kernel_launch(void* const* d_in, const int* in_sizes, int n_in,
                              void* d_out, int out_size, void* d_ws, size_t ws_size,
                              hipStream_t stream) {
  const float* x  = (const float*)d_in[0];
  const float* W0 = (const float*)d_in[1];
  const float* W1 = (const float*)d_in[2];
  const float* W2 = (const float*)d_in[3];
  const float* W3 = (const float*)d_in[4];
  const float* bi = (const float*)d_in[5];
  const float* bf = (const float*)d_in[6];
  const float* bc = (const float*)d_in[7];
  const float* bo = (const float*)d_in[8];
  const float* fcw = (const float*)d_in[9];
  const float* fcb = (const float*)d_in[10];
  float* out = (float*)d_out;

  char* ws = (char*)d_ws;
  pack_xq<<<dim3(32768), dim3(64), 0, stream>>>(x, (u8*)(ws + OFF_XBQ),
                                                (float*)(ws + OFF_SXG));
  calc_scales<<<dim3(32), dim3(256), 0, stream>>>(W0, W1, W2, W3, (float*)(ws + OFF_SCL));
  pack_whq<<<dim3(1024), dim3(256), 0, stream>>>(W0, W1, W2, W3,
                                                 (const float*)(ws + OFF_SCL),
                                                 (u8*)(ws + OFF_WHQ));
  pack_wxq<<<dim3(512), dim3(256), 0, stream>>>(W0, W1, W2, W3,
                                                (const float*)(ws + OFF_SCL),
                                                (u8*)(ws + OFF_WXQ));
  // zero himg + tags + ctl (contiguous: 524288 + 32768 + 512)
  hipMemsetAsync(ws + OFF_HIMG, 0, 524288 + 32768 + 512, stream);
  lstm_main<<<dim3(256), dim3(192), 0, stream>>>(ws, bi, bf, bc, bo, fcw, fcb, out);
}